// Round 6
// baseline (232.587 us; speedup 1.0000x reference)
//
#include <hip/hip_runtime.h>
#include <math.h>

#pragma clang fp contract(off)

#define NIMG 16
#define NP   8732
#define NCLS 81
#define NFG  80
#define KTOP 1000
#define KPAD 1024
#define DETS 100
#define CAPMAX 166912          // >= 19*8732 (hard bound: <=19 softmax scores can exceed 0.05)
#define BASEBITS 0x3D000000u   // float bits of 0.03125, below 0.05 threshold; low 13 bits zero
#define CNT_STRIDE 64          // u32 units -> 256 B per image counter (own cacheline)
#define TILEB 137              // blocks per image in k_decode (137*64 >= 8732)

// ---- workspace layout (bytes) ----
#define OFF_BOXES  0u            // [NIMG][NP][4] f32 = 2,235,392
#define OFF_CNT    2235392u      // [NIMG] u32 @256B  = 4,096   (candidate counters)
#define OFF_SCNT   2239488u      // [NIMG] u32 @256B  = 4,096   (survivor counters)
#define OFF_GHIST  2243584u      // [NIMG][8192] u32  = 524,288 (global coarse hist)
#define OFF_SBUF   2767872u      // [NIMG][2048] u64  = 262,144 (survivors)
#define OFF_T      3030016u      // [NIMG] u32 (256B pad)
#define OFF_CSCORE 3030272u      // [NIMG][KPAD] f32
#define OFF_CLABEL 3095808u      // [NIMG][KPAD] i32
#define OFF_CBOX   3161344u      // [NIMG][KPAD] float4
#define OFF_COFFS  3423488u      // [NIMG][KPAD] float4
#define OFF_CAREA  3685632u      // [NIMG][KPAD] f32
#define OFF_VALIDW 3751168u      // [NIMG][16] u64
#define OFF_MASK   3753216u      // [NIMG][16][KPAD] u64 column-major = 2,097,152
#define OFF_CAND   5850368u      // [NIMG][cap] u64
#define MEMSET_LEN 532480u       // cnt + scnt + ghist

typedef unsigned long long u64;
typedef unsigned int u32;

#define AS_GLOBAL __attribute__((address_space(1)))
#define AS_LOCAL  __attribute__((address_space(3)))

// ============================================================ kernel 1
// thread-per-prior, FLAT LDS staging via async global_load_lds (width 16).
// Also builds the per-image coarse score-bit histogram (R6): bins of exact
// emitted score bits >> 13, so k_findc needs no pass over candidates.
__global__ __launch_bounds__(64, 2) void k_decode(
    const float* __restrict__ logits, const float* __restrict__ rel,
    const float* __restrict__ priors, const int* __restrict__ tsz,
    float* __restrict__ boxes_out, u64* __restrict__ cand,
    u32* __restrict__ cnt, u32* __restrict__ ghist, int cap)
{
#pragma clang fp contract(off)
    __shared__ float lx[64 * NCLS];               // 20,736 B flat [prior][class]
    int b  = blockIdx.x / TILEB;
    int g  = blockIdx.x - b * TILEB;
    int p0 = g * 64;
    int t  = threadIdx.x;                          // single wave
    int npri = NP - p0; if (npri > 64) npri = 64;  // 64, or 28 in tail block
    int words = npri * NCLS;                       // multiple of 4

    // ---- async staging: all chunks queued before one barrier ----
    const u32* s32 = (const u32*)(logits + ((size_t)b * NP + p0) * NCLS); // 16B-aligned
    u32* lxw = (u32*)lx;
    int full = words >> 8;                         // 1KB chunks (64 lanes x 16 B)
    for (int k = 0; k < full; ++k)
        __builtin_amdgcn_global_load_lds(
            (AS_GLOBAL const u32*)(s32 + (k << 8) + (t << 2)),
            (AS_LOCAL u32*)(lxw + (k << 8)), 16, 0, 0);
    int base = full << 8;
    int c4 = (words - base) >> 6;                  // 256B chunks (64 lanes x 4 B)
    for (int k = 0; k < c4; ++k)
        __builtin_amdgcn_global_load_lds(
            (AS_GLOBAL const u32*)(s32 + base + (k << 6) + t),
            (AS_LOCAL u32*)(lxw + base + (k << 6)), 4, 0, 0);
    base += c4 << 6;
    if (t < words - base) lxw[base + t] = s32[base + t];

    int p = p0 + t;
    bool active = p < NP;

    // ---- box decode (per-thread, coalesced float4) ----
    int size_ok = 0;
    if (active) {
        float4 pr = ((const float4*)priors)[p];
        float4 rl = ((const float4*)rel)[(size_t)b * NP + p];
        float W = (float)tsz[b * 2 + 1], H = (float)tsz[b * 2 + 0];
        float cx = pr.x + (rl.x * 0.1f) * pr.z;
        float cy = pr.y + (rl.y * 0.1f) * pr.w;
        float w_ = pr.z * expf(rl.z * 0.2f);
        float h_ = pr.w * expf(rl.w * 0.2f);
        float4 bx;
        bx.x = (cx - 0.5f * w_) * W; bx.y = (cy - 0.5f * h_) * H;
        bx.z = (cx + 0.5f * w_) * W; bx.w = (cy + 0.5f * h_) * H;
        ((float4*)boxes_out)[(size_t)b * NP + p] = bx;
        size_ok = ((bx.z - bx.x) >= 0.01f) && ((bx.w - bx.y) >= 0.01f);
    }
    __syncthreads();                               // drains vmcnt for the LDS DMA

    // ---- own row -> registers (conflict-free: stride 81 odd) ----
    int tb = t * NCLS;
    float x[NCLS];
    #pragma unroll
    for (int c = 0; c < NCLS; ++c) x[c] = lx[tb + c];

    float m0 = x[0], m1 = x[1], m2 = x[2], m3 = x[3];
    #pragma unroll
    for (int c = 4; c + 3 < NCLS; c += 4) {
        m0 = fmaxf(m0, x[c]);     m1 = fmaxf(m1, x[c + 1]);
        m2 = fmaxf(m2, x[c + 2]); m3 = fmaxf(m3, x[c + 3]);
    }
    m0 = fmaxf(m0, x[80]);
    float m = fmaxf(fmaxf(m0, m1), fmaxf(m2, m3));

    float s0 = 0.f, s1 = 0.f, s2 = 0.f, s3 = 0.f;
    #pragma unroll
    for (int c = 0; c + 3 < NCLS; c += 4) {
        x[c]     = expf(x[c]     - m); s0 += x[c];
        x[c + 1] = expf(x[c + 1] - m); s1 += x[c + 1];
        x[c + 2] = expf(x[c + 2] - m); s2 += x[c + 2];
        x[c + 3] = expf(x[c + 3] - m); s3 += x[c + 3];
    }
    x[80] = expf(x[80] - m); s0 += x[80];
    float s = (s0 + s1) + (s2 + s3);

    // threshold: conservative band, exact f32-div fallback only inside band.
    float hi = 0.05000075f * s;
    float lo = 0.04999925f * s;
    u64 bits_lo = 0, band_lo = 0;
    u32 bits_hi = 0, band_hi = 0;
    if (active && size_ok) {
        #pragma unroll
        for (int c = 1; c < NCLS; ++c) {
            float e = x[c];
            bool pass = e > hi;
            bool band = (!pass) && (e > lo);
            int cm1 = c - 1;
            if (cm1 < 64) {
                bits_lo |= ((u64)pass) << cm1;
                band_lo |= ((u64)band) << cm1;
            } else {
                bits_hi |= ((u32)pass) << (cm1 - 64);
                band_hi |= ((u32)band) << (cm1 - 64);
            }
        }
    }
    while (band_lo) {
        int cm1 = __builtin_ctzll(band_lo); band_lo &= band_lo - 1;
        float e = expf(lx[tb + cm1 + 1] - m);
        if (e / s > 0.05f) bits_lo |= 1ULL << cm1;
    }
    while (band_hi) {
        int j = __builtin_ctz(band_hi); band_hi &= band_hi - 1;
        float e = expf(lx[tb + j + 65] - m);
        if (e / s > 0.05f) bits_hi |= 1u << j;
    }
    int cnt_t = __popcll(bits_lo) + __popc(bits_hi);

    int pre = cnt_t;
    #pragma unroll
    for (int d = 1; d < 64; d <<= 1) {
        int o = __shfl_up(pre, d);
        if (t >= d) pre += o;
    }
    u32 wbase = 0;
    if (t == 63) wbase = (pre > 0) ? atomicAdd(cnt + b * CNT_STRIDE, (u32)pre) : 0u;
    wbase = (u32)__shfl((int)wbase, 63);
    u32 pos = wbase + (u32)(pre - cnt_t);

    u64* cb = cand + (size_t)b * cap;
    u32* gh = ghist + b * 8192;
    u32 flatneg = 0xFFFFFFFFu - (u32)p * NFG;
    while (bits_lo) {
        int cm1 = __builtin_ctzll(bits_lo); bits_lo &= bits_lo - 1;
        float e = expf(lx[tb + cm1 + 1] - m);
        float d = e / s;
        if ((int)pos < cap) {
            u32 sb = __float_as_uint(d);
            cb[pos] = ((u64)sb << 32) | (u64)(flatneg - (u32)cm1);
            atomicAdd(gh + ((sb - BASEBITS) >> 13), 1u);
        }
        ++pos;
    }
    while (bits_hi) {
        int j = __builtin_ctz(bits_hi); bits_hi &= bits_hi - 1;
        int cm1 = j + 64;
        float e = expf(lx[tb + cm1 + 1] - m);
        float d = e / s;
        if ((int)pos < cap) {
            u32 sb = __float_as_uint(d);
            cb[pos] = ((u64)sb << 32) | (u64)(flatneg - (u32)cm1);
            atomicAdd(gh + ((sb - BASEBITS) >> 13), 1u);
        }
        ++pos;
    }
}

// ============================================================ suffix_find
// hierarchical suffix scan over 8192-bin LDS hist; finds boundary bin where
// suffix-count crosses K. hist preserved (read-only).
__device__ __forceinline__ void suffix_find(
    u32* hist, u32* wt, u32 K, int tid,
    volatile int* outI, volatile u32* outNext)
{
    int lane = tid & 63, w = tid >> 6;
    u32 v[8]; u32 tot = 0;
    #pragma unroll
    for (int k = 0; k < 8; ++k) { v[k] = hist[tid * 8 + k]; tot += v[k]; }
    u32 ws = tot;
    #pragma unroll
    for (int d = 1; d < 64; d <<= 1) {
        u32 o = __shfl_down(ws, d);
        if (lane + d < 64) ws += o;
    }
    if (lane == 0) wt[w] = ws;
    __syncthreads();
    u32 tail = 0;
    for (int w2 = w + 1; w2 < 16; ++w2) tail += wt[w2];
    u32 after = (ws - tot) + tail;
    u32 sufk[9];
    sufk[8] = after;
    #pragma unroll
    for (int k = 7; k >= 0; --k) sufk[k] = v[k] + sufk[k + 1];
    #pragma unroll
    for (int k = 0; k < 8; ++k) {
        if (sufk[k] >= K && sufk[k + 1] < K) {
            *outI = tid * 8 + k;
            *outNext = sufk[k + 1];
        }
    }
    __syncthreads();
}

// ============================================================ kernel 2a
// per-image threshold from the prebuilt global histogram. Common path needs
// NO pass over candidates (coarse threshold, survivors <= 2048 checked);
// rare fallback refines within bin c via one candidate pass.
__global__ __launch_bounds__(1024) void k_findc(
    const u32* __restrict__ ghist, const u64* __restrict__ cand,
    const u32* __restrict__ cnt, u32* __restrict__ Tarr, int cap)
{
    __shared__ u32 hist[8192];
    __shared__ u32 wt[16];
    __shared__ int sh_c, sh_i2;
    __shared__ u32 sh_nhi, sh_dummy;
    int b = blockIdx.x, tid = threadIdx.x;
    const u32* gh = ghist + b * 8192;
    for (int i = tid; i < 8192; i += 1024) hist[i] = gh[i];
    if (tid == 0) { sh_c = -2; sh_i2 = -2; sh_nhi = 0; }
    __syncthreads();
    suffix_find(hist, wt, (u32)KTOP, tid, &sh_c, &sh_nhi);
    int c = sh_c;
    u32 T = 0;
    if (c >= 0) {
        u32 nhi = sh_nhi;
        u32 count_c = hist[c];
        if (count_c + nhi <= 2048u) {
            T = BASEBITS + ((u32)c << 13);         // common path: no refine
        } else {                                   // rare: fine pass over cands
            u32 n = min(cnt[b * CNT_STRIDE], (u32)cap);
            const u64* cb = cand + (size_t)b * cap;
            __syncthreads();
            for (int i = tid; i < 8192; i += 1024) hist[i] = 0;
            __syncthreads();
            for (u32 i = tid; i < n; i += 1024) {
                u32 bits = (u32)(cb[i] >> 32);
                if ((int)((bits - BASEBITS) >> 13) == c)
                    atomicAdd(&hist[bits & 0x1FFFu], 1u);
            }
            __syncthreads();
            suffix_find(hist, wt, (u32)KTOP - nhi, tid, &sh_i2, &sh_dummy);
            T = (sh_i2 >= 0) ? (BASEBITS + ((u32)c << 13) + (u32)sh_i2) : 0u;
        }
    }
    if (tid == 0) Tarr[b * CNT_STRIDE] = T;
}

// ============================================================ kernel 2b
// parallel survivor compaction: 16 blocks per image, ballot + 1 atomic/wave.
__global__ __launch_bounds__(256) void k_compact(
    const u64* __restrict__ cand, const u32* __restrict__ cnt,
    const u32* __restrict__ Tarr, u64* __restrict__ sbuf,
    u32* __restrict__ scnt, int cap)
{
    int b = blockIdx.x >> 4, sl = blockIdx.x & 15;
    int tid = threadIdx.x, lane = tid & 63;
    u32 n = min(cnt[b * CNT_STRIDE], (u32)cap);
    u32 T = Tarr[b * CNT_STRIDE];
    const u64* cb = cand + (size_t)b * cap;
    u64* sb = sbuf + b * 2048;
    u32 lo = (u32)(((u64)n * (u32)sl) >> 4);
    u32 hi = (u32)(((u64)n * (u32)(sl + 1)) >> 4);
    for (u32 basei = lo; basei < hi; basei += 256) {
        u32 i = basei + (u32)tid;
        u64 key = (i < hi) ? cb[i] : 0ULL;
        bool pick = (i < hi) && ((u32)(key >> 32) >= T);
        u64 bal = __ballot(pick);
        u32 wb = 0;
        if (lane == 0 && bal) wb = atomicAdd(scnt + b * CNT_STRIDE, (u32)__popcll(bal));
        wb = (u32)__shfl((int)wb, 0);
        if (pick) {
            u32 pos = wb + (u32)__popcll(bal & ((1ULL << lane) - 1ULL));
            if (pos < 2048) sb[pos] = key;
        }
    }
}

// ============================================================ kernel 2c
// sort <=2048 survivors (bitonic, full-key desc) + fused prep.
__global__ __launch_bounds__(1024) void k_sort(
    const u64* __restrict__ sbuf, const u32* __restrict__ scnt,
    const float* __restrict__ boxes,
    float* __restrict__ cscore, int* __restrict__ clabel,
    float4* __restrict__ cbox, float4* __restrict__ coffs,
    float* __restrict__ carea, u64* __restrict__ validw)
{
#pragma clang fp contract(off)
    __shared__ u64 buf[2048];
    __shared__ float red[1024];
    int b = blockIdx.x, tid = threadIdx.x;
    int lane = tid & 63;
    u32 m = min(scnt[b * CNT_STRIDE], 2048u);
    const u64* sb = sbuf + b * 2048;
    for (int i = tid; i < 2048; i += 1024) buf[i] = ((u32)i < m) ? sb[i] : 0ULL;
    __syncthreads();
    for (int k = 2; k <= 2048; k <<= 1) {
        for (int j = k >> 1; j > 0; j >>= 1) {
            for (int i = tid; i < 2048; i += 1024) {
                int ixj = i ^ j;
                if (ixj > i) {
                    u64 a = buf[i], bb = buf[ixj];
                    bool up = (i & k) == 0;
                    if (up ? (a < bb) : (a > bb)) { buf[i] = bb; buf[ixj] = a; }
                }
            }
            __syncthreads();
        }
    }
    // ---- fused prep: tid owns slot tid of KPAD ----
    u64 key = (tid < KTOP) ? buf[tid] : 0ULL;
    float s = __uint_as_float((u32)(key >> 32));
    bool valid = s > 0.0f;
    u32 flat = valid ? (0xFFFFFFFFu - (u32)key) : 0u;
    int prior = (int)(flat / NFG);
    int cls = (int)(flat - (u32)prior * NFG) + 1;
    float4 bx = make_float4(0.f, 0.f, 0.f, 0.f);
    if (valid) bx = ((const float4*)boxes)[b * NP + prior];
    cscore[b * KPAD + tid] = s;
    clabel[b * KPAD + tid] = cls;
    cbox[b * KPAD + tid] = bx;
    u64 vb = __ballot(valid);
    if (lane == 0) validw[b * 16 + (tid >> 6)] = vb;
    float lm = valid ? fmaxf(fmaxf(bx.x, bx.y), fmaxf(bx.z, bx.w)) : 0.0f;
    red[tid] = fmaxf(lm, 0.0f);
    __syncthreads();
    for (int d = 512; d > 0; d >>= 1) {
        if (tid < d) red[tid] = fmaxf(red[tid], red[tid + d]);
        __syncthreads();
    }
    float mc = red[0];
    float off = (float)cls * (mc + 1.0f);
    float4 ob = valid ? make_float4(bx.x + off, bx.y + off, bx.z + off, bx.w + off)
                      : make_float4(0.f, 0.f, 0.f, 0.f);
    float area = valid ? (ob.z - ob.x) * (ob.w - ob.y) : 0.0f;
    coffs[b * KPAD + tid] = ob;
    carea[b * KPAD + tid] = area;
}

// ============================================================ kernel 4
// suppression bitmask, COLUMN-major: cmask[b][w][j] bit k = row (64w+k)
// suppresses column j.
__global__ __launch_bounds__(1024) void k_iou(
    const float4* __restrict__ coffs, const float* __restrict__ carea,
    u64* __restrict__ cmask)
{
#pragma clang fp contract(off)
    __shared__ float4 bs[KPAD];
    __shared__ float as_[KPAD];
    int b = blockIdx.x >> 4, tile = blockIdx.x & 15;
    int t = threadIdx.x;
    bs[t] = coffs[b * KPAD + t];
    as_[t] = carea[b * KPAD + t];
    __syncthreads();
    int j = tile * 64 + (t & 63);                  // column (suppressee)
    int w = t >> 6;                                // row word
    float4 bj = bs[j];
    float aj = as_[j];
    int r0 = w * 64;
    u64 bits = 0;
    #pragma unroll 4
    for (int k = 0; k < 64; ++k) {
        int r = r0 + k;                            // wave-uniform row
        float4 br = bs[r];
        float ar = as_[r];
        float ltx = fmaxf(br.x, bj.x), lty = fmaxf(br.y, bj.y);
        float rbx = fminf(br.z, bj.z), rby = fminf(br.w, bj.w);
        float wx = fmaxf(rbx - ltx, 0.0f), wy = fmaxf(rby - lty, 0.0f);
        float inter = wx * wy;
        float denom = ((ar + aj) - inter) + 1e-9f;
        float iou = inter / denom;
        bool sup = (iou > 0.45f) && (j > r);
        bits |= ((u64)sup) << k;
    }
    cmask[((size_t)b * 16 + w) * KPAD + j] = bits;
}

// ============================================================ kernel 5
// NMS via ballot fixpoint (greedy kept-set = unique fixpoint; typ. <5 iters).
__global__ __launch_bounds__(64) void k_nms(
    const u64* __restrict__ cmask, const u64* __restrict__ validw,
    const float* __restrict__ cscore, const int* __restrict__ clabel,
    const float4* __restrict__ cbox, float* __restrict__ out)
{
    int b = blockIdx.x, lane = threadIdx.x;
    const u64* cm = cmask + (size_t)b * 16 * KPAD;
    u64 kept[16];
    u64 cw[16];
    #pragma unroll
    for (int w = 0; w < 16; ++w) cw[w] = cm[w * KPAD + lane];   // group 0 cols
    #pragma unroll
    for (int g = 0; g < 16; ++g) {
        u64 vg = validw[b * 16 + g];
        bool rem = false;
        #pragma unroll
        for (int w = 0; w < 16; ++w)
            if (w < g) rem |= (kept[w] & cw[w]) != 0ULL;
        u64 cg = cw[g];
        bool myv = ((vg >> lane) & 1ULL) && !rem;
        if (g < 15) {                               // prefetch next group's cols
            int cbase = (g + 1) * 64 + lane;
            #pragma unroll
            for (int w = 0; w < 16; ++w) cw[w] = cm[w * KPAD + cbase];
        }
        u64 K = __ballot(myv);
        for (;;) {
            u64 K2 = __ballot(myv && ((K & cg) == 0ULL));
            if (K2 == K) break;
            K = K2;
        }
        kept[g] = K;                                // wave-uniform
    }
    __shared__ u64 sk[16];
    __shared__ int pfx[17];
    __shared__ int slot[DETS];
    if (lane == 0) {
        #pragma unroll
        for (int w = 0; w < 16; ++w) sk[w] = kept[w];
        int run = 0;
        #pragma unroll
        for (int l = 0; l < 16; ++l) { pfx[l] = run; run += __popcll(kept[l]); }
        pfx[16] = run;
    }
    __syncthreads();
    if (lane < 16) {
        int r = pfx[lane];
        u64 wv = sk[lane];
        while (wv && r < DETS) {
            int bit = __builtin_ctzll(wv);
            slot[r] = lane * 64 + bit;
            ++r;
            wv &= wv - 1;
        }
    }
    __syncthreads();
    int total = min(pfx[16], DETS);
    for (int r = lane; r < DETS; r += 64) {
        float4 bx = make_float4(0.f, 0.f, 0.f, 0.f);
        float s = 0.0f;
        int lb = -1;
        if (r < total) {
            int cdx = slot[r];
            bx = cbox[b * KPAD + cdx];
            s = cscore[b * KPAD + cdx];
            lb = clabel[b * KPAD + cdx];
        }
        float* ob = out + ((size_t)b * DETS + r) * 4;
        ob[0] = bx.x; ob[1] = bx.y; ob[2] = bx.z; ob[3] = bx.w;
        out[NIMG * DETS * 4 + b * DETS + r] = s;
        out[NIMG * DETS * 4 + NIMG * DETS + b * DETS + r] = (float)lb;
    }
}

// ============================================================ launch
extern "C" void kernel_launch(void* const* d_in, const int* in_sizes, int n_in,
                              void* d_out, int out_size, void* d_ws, size_t ws_size,
                              hipStream_t stream) {
    const float* logits = (const float*)d_in[0];
    const float* rel    = (const float*)d_in[1];
    const float* priors = (const float*)d_in[2];
    const int*   tsz    = (const int*)d_in[3];
    float* out = (float*)d_out;
    char* ws = (char*)d_ws;

    float* boxes  = (float*)(ws + OFF_BOXES);
    u32*   cnt    = (u32*)(ws + OFF_CNT);
    u32*   scnt   = (u32*)(ws + OFF_SCNT);
    u32*   ghist  = (u32*)(ws + OFF_GHIST);
    u64*   sbuf   = (u64*)(ws + OFF_SBUF);
    u32*   Tarr   = (u32*)(ws + OFF_T);
    float* cscore = (float*)(ws + OFF_CSCORE);
    int*   clabel = (int*)(ws + OFF_CLABEL);
    float4* cbox  = (float4*)(ws + OFF_CBOX);
    float4* coffs = (float4*)(ws + OFF_COFFS);
    float* carea  = (float*)(ws + OFF_CAREA);
    u64*   validw = (u64*)(ws + OFF_VALIDW);
    u64*   cmask  = (u64*)(ws + OFF_MASK);
    u64*   cand   = (u64*)(ws + OFF_CAND);

    long long avail = ((long long)ws_size - (long long)OFF_CAND) / (NIMG * 8);
    int cap = (int)(avail < CAPMAX ? (avail > 0 ? avail : 1) : CAPMAX);
    cap &= ~1;                                    // even -> 16B-aligned per-image base

    hipMemsetAsync(cnt, 0, MEMSET_LEN, stream);   // cnt + scnt + ghist
    k_decode<<<NIMG * TILEB, 64, 0, stream>>>(logits, rel, priors, tsz,
                                              boxes, cand, cnt, ghist, cap);
    k_findc<<<NIMG, 1024, 0, stream>>>(ghist, cand, cnt, Tarr, cap);
    k_compact<<<NIMG * 16, 256, 0, stream>>>(cand, cnt, Tarr, sbuf, scnt, cap);
    k_sort<<<NIMG, 1024, 0, stream>>>(sbuf, scnt, boxes, cscore, clabel,
                                      cbox, coffs, carea, validw);
    k_iou<<<NIMG * 16, 1024, 0, stream>>>(coffs, carea, cmask);
    k_nms<<<NIMG, 64, 0, stream>>>(cmask, validw, cscore, clabel, cbox, out);
}

// Round 7
// 160.362 us; speedup vs baseline: 1.4504x; 1.4504x over previous
//
#include <hip/hip_runtime.h>
#include <math.h>

#pragma clang fp contract(off)

#define NIMG 16
#define NP   8732
#define NCLS 81
#define NFG  80
#define KTOP 1000
#define KPAD 1024
#define DETS 100
#define CAPMAX 166912          // >= 19*8732 (hard bound: <=19 softmax scores can exceed 0.05)
#define BASEBITS 0x3D000000u   // float bits of 0.03125, below 0.05 threshold
#define CNT_STRIDE 64          // u32 units -> 256 B per image counter (own cacheline)
#define TILEB 137              // 64-prior tiles per image (137*64 >= 8732)
#define NBIN 1280              // coarse hist bins: (bits-BASEBITS)>>15, clamp 1279

// ---- workspace layout (bytes) ----
#define OFF_BOXES  0u            // [NIMG][NP][4] f32 = 2,235,392
#define OFF_CNT    2235392u      // [NIMG] u32 @256B (candidate counters)
#define OFF_SCNT   2239488u      // [NIMG] u32 @256B (survivor counters)
#define OFF_GHIST  2243584u      // [NIMG][1280] u32 = 81,920
#define OFF_SBUF   2325504u      // [NIMG][2048] u64 = 262,144
#define OFF_T      2587648u      // [NIMG] u32 @256B
#define OFF_CSCORE 2591744u      // [NIMG][KPAD] f32
#define OFF_CLABEL 2657280u      // [NIMG][KPAD] i32
#define OFF_CBOX   2722816u      // [NIMG][KPAD] float4
#define OFF_COFFS  2984960u      // [NIMG][KPAD] float4
#define OFF_CAREA  3247104u      // [NIMG][KPAD] f32
#define OFF_VALIDW 3312640u      // [NIMG][16] u64
#define OFF_MASK   3314688u      // [NIMG][16][KPAD] u64 column-major
#define OFF_CAND   5411840u      // [NIMG][cap] u64
#define MEMSET_LEN 90112u        // cnt + scnt + ghist (contiguous)

typedef unsigned long long u64;
typedef unsigned int u32;

#define AS_GLOBAL __attribute__((address_space(1)))
#define AS_LOCAL  __attribute__((address_space(3)))

// ============================================================ kernel 1
// 4 waves per 64-prior tile. Quarter q of prior pl handles classes c==q mod 4
// == R5's 4-accumulator interleave, so max/sum combines are bit-identical.
// R6 counters: 1-wave blocks at 20.7KB LDS -> 4.4 waves/CU, DMA-latency-bound.
// 256-thr blocks -> ~24 waves/CU at same LDS.
__global__ __launch_bounds__(256, 6) void k_decode(
    const float* __restrict__ logits, const float* __restrict__ rel,
    const float* __restrict__ priors, const int* __restrict__ tsz,
    float* __restrict__ boxes_out, u64* __restrict__ cand,
    u32* __restrict__ cnt, int cap)
{
#pragma clang fp contract(off)
    __shared__ __align__(16) float lx[64 * NCLS];   // 20,736 B flat [prior][class]
    __shared__ float pmx[4 * 64];
    __shared__ float psm[4 * 64];
    __shared__ u32 sok[64];
    __shared__ u32 wtt[4];
    __shared__ u32 sbase;
    int b  = blockIdx.x / TILEB;
    int g  = blockIdx.x - b * TILEB;
    int p0 = g * 64;
    int t  = threadIdx.x;
    int lane = t & 63;
    int q = t >> 6;
    int npri = NP - p0; if (npri > 64) npri = 64;
    int words = npri * NCLS;

    // ---- async staging: chunks split across the 4 waves, one barrier ----
    const u32* s32 = (const u32*)(logits + ((size_t)b * NP + p0) * NCLS);
    u32* lxw = (u32*)lx;
    int full = words >> 8;                          // 1KB chunks (64 x 16 B)
    for (int k = q; k < full; k += 4)
        __builtin_amdgcn_global_load_lds(
            (AS_GLOBAL const u32*)(s32 + (k << 8) + (lane << 2)),
            (AS_LOCAL u32*)(lxw + (k << 8)), 16, 0, 0);
    int base = full << 8;
    int c4 = (words - base) >> 6;                   // 256B chunks (64 x 4 B)
    for (int k = q; k < c4; k += 4)
        __builtin_amdgcn_global_load_lds(
            (AS_GLOBAL const u32*)(s32 + base + (k << 6) + lane),
            (AS_LOCAL u32*)(lxw + base + (k << 6)), 4, 0, 0);
    int base2 = base + (c4 << 6);
    if (q == 0 && lane < words - base2) lxw[base2 + lane] = s32[base2 + lane];

    int p = p0 + lane;
    bool active = p < NP;

    // ---- box decode by wave 0 (independent of LDS; overlaps DMA) ----
    if (q == 0) {
        u32 ok = 0;
        if (active) {
            float4 pr = ((const float4*)priors)[p];
            float4 rl = ((const float4*)rel)[(size_t)b * NP + p];
            float W = (float)tsz[b * 2 + 1], H = (float)tsz[b * 2 + 0];
            float cx = pr.x + (rl.x * 0.1f) * pr.z;
            float cy = pr.y + (rl.y * 0.1f) * pr.w;
            float w_ = pr.z * expf(rl.z * 0.2f);
            float h_ = pr.w * expf(rl.w * 0.2f);
            float4 bx;
            bx.x = (cx - 0.5f * w_) * W; bx.y = (cy - 0.5f * h_) * H;
            bx.z = (cx + 0.5f * w_) * W; bx.w = (cy + 0.5f * h_) * H;
            ((float4*)boxes_out)[(size_t)b * NP + p] = bx;
            ok = ((bx.z - bx.x) >= 0.01f) && ((bx.w - bx.y) >= 0.01f);
        }
        sok[lane] = ok;
    }
    __syncthreads();                                 // #1: DMA drained + sok

    // ---- quarter's classes -> registers (stride-81 rows, conflict-free) ----
    int tb = lane * NCLS;
    int nk = (q == 0) ? 21 : 20;                     // q==0 also owns c=80
    float x[21];
    #pragma unroll
    for (int k = 0; k < 21; ++k) {
        int c = q + 4 * k;
        x[k] = (k < nk) ? lx[tb + c] : -3.4e38f;
    }
    float pm = -3.4e38f;
    #pragma unroll
    for (int k = 0; k < 21; ++k) if (k < nk) pm = fmaxf(pm, x[k]);
    pmx[q * 64 + lane] = pm;
    __syncthreads();                                 // #2: partial max
    float m = fmaxf(fmaxf(pmx[lane], pmx[64 + lane]),
                    fmaxf(pmx[128 + lane], pmx[192 + lane]));

    float ps = 0.f;
    #pragma unroll
    for (int k = 0; k < 21; ++k) {
        if (k < nk) { x[k] = expf(x[k] - m); ps += x[k]; }
    }
    psm[q * 64 + lane] = ps;
    __syncthreads();                                 // #3: partial sum
    float s = (psm[lane] + psm[64 + lane]) + (psm[128 + lane] + psm[192 + lane]);

    // threshold: conservative band; exact f32-div fallback inside band only
    float hi = 0.05000075f * s;
    float lo = 0.04999925f * s;
    u32 pass = 0, band = 0;
    u32 sizeok = sok[lane];
    if (active && sizeok) {
        #pragma unroll
        for (int k = 0; k < 21; ++k) {
            int c = q + 4 * k;
            if (k < nk && c >= 1) {
                bool pa = x[k] > hi;
                bool bd = (!pa) && (x[k] > lo);
                pass |= ((u32)pa) << k;
                band |= ((u32)bd) << k;
            }
        }
    }
    while (band) {
        int k = __builtin_ctz(band); band &= band - 1;
        int c = q + 4 * k;
        float e = expf(lx[tb + c] - m);
        if (e / s > 0.05f) pass |= 1u << k;
    }
    int cnt_t = __popc(pass);

    // 256-thread prefix: wave scan + wave totals + one atomic per block
    int pre = cnt_t;
    #pragma unroll
    for (int d = 1; d < 64; d <<= 1) {
        int o = __shfl_up(pre, d);
        if (lane >= d) pre += o;
    }
    if (lane == 63) wtt[q] = (u32)pre;
    __syncthreads();                                 // #4: wave totals
    u32 before = 0;
    for (int w = 0; w < 4; ++w) if (w < q) before += wtt[w];
    if (t == 0) {
        u32 tot = wtt[0] + wtt[1] + wtt[2] + wtt[3];
        sbase = tot ? atomicAdd(cnt + b * CNT_STRIDE, tot) : 0u;
    }
    __syncthreads();                                 // #5: block base
    u32 pos = sbase + before + (u32)(pre - cnt_t);

    u64* cb = cand + (size_t)b * cap;
    u32 flatneg = 0xFFFFFFFFu - (u32)p * NFG;
    while (pass) {
        int k = __builtin_ctz(pass); pass &= pass - 1;
        int c = q + 4 * k;
        float e = expf(lx[tb + c] - m);
        float d = e / s;
        if ((int)pos < cap)
            cb[pos] = ((u64)__float_as_uint(d) << 32) | (u64)(flatneg - (u32)(c - 1));
        ++pos;
    }
}

// ============================================================ kernel 2a
// parallel coarse hist: 16 blocks/image, LDS-aggregated, ~150 global
// atomics per block (vs R6's 500K inline per-candidate atomics).
__global__ __launch_bounds__(256) void k_hist(
    const u64* __restrict__ cand, const u32* __restrict__ cnt,
    u32* __restrict__ ghist, int cap)
{
    __shared__ u32 h[NBIN];
    int b = blockIdx.x >> 4, sl = blockIdx.x & 15;
    int t = threadIdx.x;
    for (int i = t; i < NBIN; i += 256) h[i] = 0;
    u32 n = min(cnt[b * CNT_STRIDE], (u32)cap);
    __syncthreads();
    const u64* cb = cand + (size_t)b * cap;
    u32 lo = (u32)(((u64)n * (u32)sl) >> 4);
    u32 hi = (u32)(((u64)n * (u32)(sl + 1)) >> 4);
    for (u32 i = lo + (u32)t; i < hi; i += 256) {
        u32 sb = (u32)(cb[i] >> 32);
        u32 bin = (sb - BASEBITS) >> 15;
        if (bin > NBIN - 1) bin = NBIN - 1;
        atomicAdd(&h[bin], 1u);
    }
    __syncthreads();
    for (int i = t; i < NBIN; i += 256)
        if (h[i]) atomicAdd(ghist + b * NBIN + i, h[i]);
}

// ============================================================ suffix_find
// (used only by the rare fine-fallback path of k_findc)
__device__ __forceinline__ void suffix_find(
    u32* hist, u32* wt, u32 K, int tid,
    volatile int* outI, volatile u32* outNext)
{
    int lane = tid & 63, w = tid >> 6;
    u32 v[8]; u32 tot = 0;
    #pragma unroll
    for (int k = 0; k < 8; ++k) { v[k] = hist[tid * 8 + k]; tot += v[k]; }
    u32 ws = tot;
    #pragma unroll
    for (int d = 1; d < 64; d <<= 1) {
        u32 o = __shfl_down(ws, d);
        if (lane + d < 64) ws += o;
    }
    if (lane == 0) wt[w] = ws;
    __syncthreads();
    u32 tail = 0;
    for (int w2 = w + 1; w2 < 16; ++w2) tail += wt[w2];
    u32 after = (ws - tot) + tail;
    u32 sufk[9];
    sufk[8] = after;
    #pragma unroll
    for (int k = 7; k >= 0; --k) sufk[k] = v[k] + sufk[k + 1];
    #pragma unroll
    for (int k = 0; k < 8; ++k) {
        if (sufk[k] >= K && sufk[k + 1] < K) {
            *outI = tid * 8 + k;
            *outNext = sufk[k + 1];
        }
    }
    __syncthreads();
}

// ============================================================ kernel 2b
// threshold from the 1280-bin hist (wave-0 suffix scan). Common path: coarse
// T, no candidate pass (survivors = S(c) <= 2048). Rare: fine pass in bin c.
__global__ __launch_bounds__(1024) void k_findc(
    const u32* __restrict__ ghist, const u64* __restrict__ cand,
    const u32* __restrict__ cnt, u32* __restrict__ Tarr, int cap)
{
    __shared__ u32 h[NBIN];
    __shared__ u32 fh[8192];
    __shared__ u32 wt[16];
    __shared__ int sh_c, sh_i2;
    __shared__ u32 sh_S, sh_next, sh_d;
    int b = blockIdx.x, t = threadIdx.x;
    for (int i = t; i < NBIN; i += 1024) h[i] = ghist[b * NBIN + i];
    if (t == 0) { sh_c = -2; sh_i2 = -2; sh_S = 0; sh_next = 0; }
    __syncthreads();
    if (t < 64) {                                   // wave 0: 20 bins/lane
        u32 v[20]; u32 tot = 0;
        #pragma unroll
        for (int k = 0; k < 20; ++k) { v[k] = h[t * 20 + k]; tot += v[k]; }
        u32 ws = tot;
        #pragma unroll
        for (int d = 1; d < 64; d <<= 1) {
            u32 o = (u32)__shfl_down((int)ws, d);
            if (t + d < 64) ws += o;
        }
        u32 suf[21];
        suf[20] = ws - tot;                          // suffix after my bins
        #pragma unroll
        for (int k = 19; k >= 0; --k) suf[k] = v[k] + suf[k + 1];
        #pragma unroll
        for (int k = 0; k < 20; ++k) {
            if (suf[k] >= (u32)KTOP && suf[k + 1] < (u32)KTOP) {
                sh_c = t * 20 + k; sh_S = suf[k]; sh_next = suf[k + 1];
            }
        }
    }
    __syncthreads();
    int c = sh_c;
    u32 T = 0;
    if (c >= 0) {
        if (sh_S <= 2048u) {
            T = BASEBITS + ((u32)c << 15);           // common path
        } else {                                     // rare fine pass
            u32 nhi = sh_next;
            for (int i = t; i < 8192; i += 1024) fh[i] = 0;
            __syncthreads();
            u32 n = min(cnt[b * CNT_STRIDE], (u32)cap);
            const u64* cb = cand + (size_t)b * cap;
            for (u32 i = (u32)t; i < n; i += 1024) {
                u32 sb = (u32)(cb[i] >> 32);
                if ((int)((sb - BASEBITS) >> 15) == c)
                    atomicAdd(&fh[(sb >> 2) & 0x1FFFu], 1u);
            }
            __syncthreads();
            suffix_find(fh, wt, (u32)KTOP - nhi, t, &sh_i2, &sh_d);
            T = (sh_i2 >= 0) ? (BASEBITS + ((u32)c << 15) + ((u32)sh_i2 << 2))
                             : (BASEBITS + ((u32)c << 15));
        }
    }
    if (t == 0) Tarr[b * CNT_STRIDE] = T;
}

// ============================================================ kernel 2c
// parallel survivor compaction: 16 blocks/image, ballot + 1 atomic/wave.
__global__ __launch_bounds__(256) void k_compact(
    const u64* __restrict__ cand, const u32* __restrict__ cnt,
    const u32* __restrict__ Tarr, u64* __restrict__ sbuf,
    u32* __restrict__ scnt, int cap)
{
    int b = blockIdx.x >> 4, sl = blockIdx.x & 15;
    int tid = threadIdx.x, lane = tid & 63;
    u32 n = min(cnt[b * CNT_STRIDE], (u32)cap);
    u32 T = Tarr[b * CNT_STRIDE];
    const u64* cb = cand + (size_t)b * cap;
    u64* sb = sbuf + b * 2048;
    u32 lo = (u32)(((u64)n * (u32)sl) >> 4);
    u32 hi = (u32)(((u64)n * (u32)(sl + 1)) >> 4);
    for (u32 basei = lo; basei < hi; basei += 256) {
        u32 i = basei + (u32)tid;
        u64 key = (i < hi) ? cb[i] : 0ULL;
        bool pick = (i < hi) && ((u32)(key >> 32) >= T);
        u64 bal = __ballot(pick);
        u32 wb = 0;
        if (lane == 0 && bal) wb = atomicAdd(scnt + b * CNT_STRIDE, (u32)__popcll(bal));
        wb = (u32)__shfl((int)wb, 0);
        if (pick) {
            u32 pos = wb + (u32)__popcll(bal & ((1ULL << lane) - 1ULL));
            if (pos < 2048) sb[pos] = key;
        }
    }
}

// ============================================================ kernel 2d
// bitonic sort (size 1024 when survivors <=1024, else 2048) + fused prep.
__global__ __launch_bounds__(1024) void k_sort(
    const u64* __restrict__ sbuf, const u32* __restrict__ scnt,
    const float* __restrict__ boxes,
    float* __restrict__ cscore, int* __restrict__ clabel,
    float4* __restrict__ cbox, float4* __restrict__ coffs,
    float* __restrict__ carea, u64* __restrict__ validw)
{
#pragma clang fp contract(off)
    __shared__ u64 buf[2048];
    __shared__ float red[1024];
    int b = blockIdx.x, tid = threadIdx.x;
    int lane = tid & 63;
    u32 m = min(scnt[b * CNT_STRIDE], 2048u);
    int size = (m > 1024u) ? 2048 : 1024;
    const u64* sb = sbuf + b * 2048;
    for (int i = tid; i < size; i += 1024) buf[i] = ((u32)i < m) ? sb[i] : 0ULL;
    __syncthreads();
    for (int k = 2; k <= size; k <<= 1) {
        for (int j = k >> 1; j > 0; j >>= 1) {
            for (int i = tid; i < size; i += 1024) {
                int ixj = i ^ j;
                if (ixj > i) {
                    u64 a = buf[i], bb = buf[ixj];
                    bool up = (i & k) == 0;
                    if (up ? (a < bb) : (a > bb)) { buf[i] = bb; buf[ixj] = a; }
                }
            }
            __syncthreads();
        }
    }
    // ---- fused prep: tid owns slot tid of KPAD ----
    u64 key = (tid < KTOP) ? buf[tid] : 0ULL;
    float s = __uint_as_float((u32)(key >> 32));
    bool valid = s > 0.0f;
    u32 flat = valid ? (0xFFFFFFFFu - (u32)key) : 0u;
    int prior = (int)(flat / NFG);
    int cls = (int)(flat - (u32)prior * NFG) + 1;
    float4 bx = make_float4(0.f, 0.f, 0.f, 0.f);
    if (valid) bx = ((const float4*)boxes)[b * NP + prior];
    cscore[b * KPAD + tid] = s;
    clabel[b * KPAD + tid] = cls;
    cbox[b * KPAD + tid] = bx;
    u64 vb = __ballot(valid);
    if (lane == 0) validw[b * 16 + (tid >> 6)] = vb;
    float lm = valid ? fmaxf(fmaxf(bx.x, bx.y), fmaxf(bx.z, bx.w)) : 0.0f;
    red[tid] = fmaxf(lm, 0.0f);
    __syncthreads();
    for (int d = 512; d > 0; d >>= 1) {
        if (tid < d) red[tid] = fmaxf(red[tid], red[tid + d]);
        __syncthreads();
    }
    float mc = red[0];
    float off = (float)cls * (mc + 1.0f);
    float4 ob = valid ? make_float4(bx.x + off, bx.y + off, bx.z + off, bx.w + off)
                      : make_float4(0.f, 0.f, 0.f, 0.f);
    float area = valid ? (ob.z - ob.x) * (ob.w - ob.y) : 0.0f;
    coffs[b * KPAD + tid] = ob;
    carea[b * KPAD + tid] = area;
}

// ============================================================ kernel 4
// suppression bitmask, COLUMN-major: cmask[b][w][j] bit k = row (64w+k)
// suppresses column j.
__global__ __launch_bounds__(1024) void k_iou(
    const float4* __restrict__ coffs, const float* __restrict__ carea,
    u64* __restrict__ cmask)
{
#pragma clang fp contract(off)
    __shared__ float4 bs[KPAD];
    __shared__ float as_[KPAD];
    int b = blockIdx.x >> 4, tile = blockIdx.x & 15;
    int t = threadIdx.x;
    bs[t] = coffs[b * KPAD + t];
    as_[t] = carea[b * KPAD + t];
    __syncthreads();
    int j = tile * 64 + (t & 63);                  // column (suppressee)
    int w = t >> 6;                                // row word
    float4 bj = bs[j];
    float aj = as_[j];
    int r0 = w * 64;
    u64 bits = 0;
    #pragma unroll 4
    for (int k = 0; k < 64; ++k) {
        int r = r0 + k;                            // wave-uniform row
        float4 br = bs[r];
        float ar = as_[r];
        float ltx = fmaxf(br.x, bj.x), lty = fmaxf(br.y, bj.y);
        float rbx = fminf(br.z, bj.z), rby = fminf(br.w, bj.w);
        float wx = fmaxf(rbx - ltx, 0.0f), wy = fmaxf(rby - lty, 0.0f);
        float inter = wx * wy;
        float denom = ((ar + aj) - inter) + 1e-9f;
        float iou = inter / denom;
        bool sup = (iou > 0.45f) && (j > r);
        bits |= ((u64)sup) << k;
    }
    cmask[((size_t)b * 16 + w) * KPAD + j] = bits;
}

// ============================================================ kernel 5
// NMS via ballot fixpoint (greedy kept-set = unique fixpoint; typ. <5 iters).
__global__ __launch_bounds__(64) void k_nms(
    const u64* __restrict__ cmask, const u64* __restrict__ validw,
    const float* __restrict__ cscore, const int* __restrict__ clabel,
    const float4* __restrict__ cbox, float* __restrict__ out)
{
    int b = blockIdx.x, lane = threadIdx.x;
    const u64* cm = cmask + (size_t)b * 16 * KPAD;
    u64 kept[16];
    u64 cw[16];
    #pragma unroll
    for (int w = 0; w < 16; ++w) cw[w] = cm[w * KPAD + lane];   // group 0 cols
    #pragma unroll
    for (int g = 0; g < 16; ++g) {
        u64 vg = validw[b * 16 + g];
        bool rem = false;
        #pragma unroll
        for (int w = 0; w < 16; ++w)
            if (w < g) rem |= (kept[w] & cw[w]) != 0ULL;
        u64 cg = cw[g];
        bool myv = ((vg >> lane) & 1ULL) && !rem;
        if (g < 15) {                               // prefetch next group's cols
            int cbase = (g + 1) * 64 + lane;
            #pragma unroll
            for (int w = 0; w < 16; ++w) cw[w] = cm[w * KPAD + cbase];
        }
        u64 K = __ballot(myv);
        for (;;) {
            u64 K2 = __ballot(myv && ((K & cg) == 0ULL));
            if (K2 == K) break;
            K = K2;
        }
        kept[g] = K;                                // wave-uniform
    }
    __shared__ u64 sk[16];
    __shared__ int pfx[17];
    __shared__ int slot[DETS];
    if (lane == 0) {
        #pragma unroll
        for (int w = 0; w < 16; ++w) sk[w] = kept[w];
        int run = 0;
        #pragma unroll
        for (int l = 0; l < 16; ++l) { pfx[l] = run; run += __popcll(kept[l]); }
        pfx[16] = run;
    }
    __syncthreads();
    if (lane < 16) {
        int r = pfx[lane];
        u64 wv = sk[lane];
        while (wv && r < DETS) {
            int bit = __builtin_ctzll(wv);
            slot[r] = lane * 64 + bit;
            ++r;
            wv &= wv - 1;
        }
    }
    __syncthreads();
    int total = min(pfx[16], DETS);
    for (int r = lane; r < DETS; r += 64) {
        float4 bx = make_float4(0.f, 0.f, 0.f, 0.f);
        float s = 0.0f;
        int lb = -1;
        if (r < total) {
            int cdx = slot[r];
            bx = cbox[b * KPAD + cdx];
            s = cscore[b * KPAD + cdx];
            lb = clabel[b * KPAD + cdx];
        }
        float* ob = out + ((size_t)b * DETS + r) * 4;
        ob[0] = bx.x; ob[1] = bx.y; ob[2] = bx.z; ob[3] = bx.w;
        out[NIMG * DETS * 4 + b * DETS + r] = s;
        out[NIMG * DETS * 4 + NIMG * DETS + b * DETS + r] = (float)lb;
    }
}

// ============================================================ launch
extern "C" void kernel_launch(void* const* d_in, const int* in_sizes, int n_in,
                              void* d_out, int out_size, void* d_ws, size_t ws_size,
                              hipStream_t stream) {
    const float* logits = (const float*)d_in[0];
    const float* rel    = (const float*)d_in[1];
    const float* priors = (const float*)d_in[2];
    const int*   tsz    = (const int*)d_in[3];
    float* out = (float*)d_out;
    char* ws = (char*)d_ws;

    float* boxes  = (float*)(ws + OFF_BOXES);
    u32*   cnt    = (u32*)(ws + OFF_CNT);
    u32*   scnt   = (u32*)(ws + OFF_SCNT);
    u32*   ghist  = (u32*)(ws + OFF_GHIST);
    u64*   sbuf   = (u64*)(ws + OFF_SBUF);
    u32*   Tarr   = (u32*)(ws + OFF_T);
    float* cscore = (float*)(ws + OFF_CSCORE);
    int*   clabel = (int*)(ws + OFF_CLABEL);
    float4* cbox  = (float4*)(ws + OFF_CBOX);
    float4* coffs = (float4*)(ws + OFF_COFFS);
    float* carea  = (float*)(ws + OFF_CAREA);
    u64*   validw = (u64*)(ws + OFF_VALIDW);
    u64*   cmask  = (u64*)(ws + OFF_MASK);
    u64*   cand   = (u64*)(ws + OFF_CAND);

    long long avail = ((long long)ws_size - (long long)OFF_CAND) / (NIMG * 8);
    int cap = (int)(avail < CAPMAX ? (avail > 0 ? avail : 1) : CAPMAX);
    cap &= ~1;                                    // even -> 16B-aligned per-image base

    hipMemsetAsync(cnt, 0, MEMSET_LEN, stream);   // cnt + scnt + ghist
    k_decode<<<NIMG * TILEB, 256, 0, stream>>>(logits, rel, priors, tsz,
                                               boxes, cand, cnt, cap);
    k_hist<<<NIMG * 16, 256, 0, stream>>>(cand, cnt, ghist, cap);
    k_findc<<<NIMG, 1024, 0, stream>>>(ghist, cand, cnt, Tarr, cap);
    k_compact<<<NIMG * 16, 256, 0, stream>>>(cand, cnt, Tarr, sbuf, scnt, cap);
    k_sort<<<NIMG, 1024, 0, stream>>>(sbuf, scnt, boxes, cscore, clabel,
                                      cbox, coffs, carea, validw);
    k_iou<<<NIMG * 16, 1024, 0, stream>>>(coffs, carea, cmask);
    k_nms<<<NIMG, 64, 0, stream>>>(cmask, validw, cscore, clabel, cbox, out);
}